// Round 7
// baseline (282.564 us; speedup 1.0000x reference)
//
#include <hip/hip_runtime.h>
#include <hip/hip_bf16.h>

typedef __attribute__((ext_vector_type(8))) short short8;
typedef __attribute__((ext_vector_type(4))) float f32x4;

static inline size_t ws_align(size_t x) { return (x + 511) & ~((size_t)511); }

static __device__ inline unsigned short f2bf(float f) {
    __hip_bfloat16 h = __float2bfloat16(f);
    return __builtin_bit_cast(unsigned short, h);
}

static __device__ inline float bf2f(unsigned short u) {
    unsigned int x = ((unsigned int)u) << 16;
    return __builtin_bit_cast(float, x);
}

// ---------------- K0: hist + wconv + flags, fused ----------------
// Blocks [0, hblocks): histogram (counts + per-edge local offset).
// Blocks [hblocks, hblocks+160): W pre-transpose to bf16 Wt[n][k] (40960 elems).
// dtype flags computed wave-locally via ballot; block 0 publishes them.

__global__ __launch_bounds__(256) void hist_wconv_kernel(const int* __restrict__ ei,
                                                         const unsigned short* __restrict__ w1s,
                                                         const void* __restrict__ W1raw,
                                                         const void* __restrict__ W2raw,
                                                         const void* __restrict__ W3raw,
                                                         int* __restrict__ counts,
                                                         int* __restrict__ loff,
                                                         int* __restrict__ flags,
                                                         unsigned short* __restrict__ wt1,
                                                         unsigned short* __restrict__ wt2,
                                                         unsigned short* __restrict__ wt3,
                                                         int E, int hblocks) {
    const int tid = threadIdx.x;
    const int lane = tid & 63;

    unsigned ew = (w1s[2 * lane] >> 7) & 0xFF;
    unsigned long long m1 = __ballot(ew >= 100 && ew <= 130);
    const int in_fp32 = (__popcll(m1) < 48) ? 1 : 0;
    unsigned long long m2 = __ballot(((const unsigned int*)ei)[2 * lane + 1] == 0u);
    const int ei64 = (__popcll(m2) >= 48) ? 1 : 0;

    if (blockIdx.x < hblocks) {
        if (blockIdx.x == 0 && tid == 0) {
            flags[0] = in_fp32;
            flags[1] = ei64;
        }
        int e = blockIdx.x * 256 + tid;
        if (e < E) {
            int d = ei64 ? ei[2 * (size_t)E + 2 * e] : ei[(size_t)E + e];
            loff[e] = atomicAdd(&counts[d], 1);
        }
        return;
    }

    // wconv part
    int idx = (blockIdx.x - hblocks) * 256 + tid;
    const void* src;
    unsigned short* dst;
    int e, fout;
    if (idx < 16384) {
        src = W1raw; dst = wt1; e = idx; fout = 128;
    } else if (idx < 32768) {
        src = W2raw; dst = wt2; e = idx - 16384; fout = 128;
    } else if (idx < 40960) {
        src = W3raw; dst = wt3; e = idx - 32768; fout = 64;
    } else {
        return;
    }
    int n = e & (fout - 1);
    int k = e / fout;
    unsigned short v;
    if (in_fp32) v = f2bf(((const float*)src)[e]);
    else         v = ((const unsigned short*)src)[e];
    dst[n * 128 + k] = v;
}

// ---------------- CSR build (alloc + fill) ----------------

__global__ __launch_bounds__(256) void alloc_kernel(const int* __restrict__ counts,
                                                    float* __restrict__ dinv,
                                                    int* __restrict__ rowptr,
                                                    int* __restrict__ total, int N) {
    int n = blockIdx.x * blockDim.x + threadIdx.x;
    int lane = threadIdx.x & 63;
    int c = (n < N) ? counts[n] : 0;
    if (n < N) {
        int d = (c < 1) ? 1 : c;
        dinv[n] = rsqrtf((float)d);
    }
    int incl = c;
#pragma unroll
    for (int off = 1; off < 64; off <<= 1) {
        int v = __shfl_up(incl, off, 64);
        if (lane >= off) incl += v;
    }
    int wavetot = __shfl(incl, 63, 64);
    int base = 0;
    if (lane == 0) base = atomicAdd(total, wavetot);
    base = __shfl(base, 0, 64);
    if (n < N) rowptr[n] = base + incl - c;
}

__global__ void fill_kernel(const int* __restrict__ ei, const int* __restrict__ flags,
                            const float* __restrict__ dinv, const int* __restrict__ rowptr,
                            const int* __restrict__ loff, int2* __restrict__ edgedat, int E) {
    int e = blockIdx.x * blockDim.x + threadIdx.x;
    if (e < E) {
        int s, d;
        if (flags[1]) {
            s = ei[2 * e];
            d = ei[2 * (size_t)E + 2 * e];
        } else {
            s = ei[e];
            d = ei[(size_t)E + e];
        }
        int pos = rowptr[d] + loff[e];
        float wt = dinv[s] * dinv[d];
        edgedat[pos] = make_int2(s, __float_as_int(wt));
    }
}

// ---------------- Fused layer: out = relu( agg(Hin) @ W )  [+ softmax if SM] ----------------
// Block = 256 thr = 4 waves = 16 nodes (4 per wave). Gather phase identical to the proven
// spmm128 (12500 waves device-wide -> full occupancy). Aggregated rows -> 4.3KB LDS tile.
// Barrier. MFMA with B-fragments read directly from L2-hot pre-transposed global Wt.
// FOUT=128: waves split the 8 col-tiles (2 each). FOUT=64+SM: wave 0 computes all 4 tiles,
// does relu+softmax per row, stores (fp32 or bf16 per flags).

template <int FOUT, bool SM>
__global__ __launch_bounds__(256) void fused_layer_kernel(const void* __restrict__ Hraw, int a_follows,
                                                          const unsigned short* __restrict__ wt,
                                                          const int2* __restrict__ edgedat,
                                                          const int* __restrict__ rowptr,
                                                          const int* __restrict__ counts,
                                                          const int* __restrict__ flags,
                                                          void* __restrict__ out, int N) {
    constexpr int LDA = 136;  // shorts; row stride 272B (16B-aligned)
    __shared__ __align__(16) unsigned short agg[16 * LDA];  // 4352 B

    const int tid = threadIdx.x;
    const int wave = tid >> 6;
    const int lane = tid & 63;
    const int grp = lane >> 4;   // 4 groups x 16 lanes
    const int gl = lane & 15;    // feature chunk gl*8 .. gl*8+7
    const int base = blockIdx.x * 16;
    const int a_fp32 = a_follows & flags[0];
    const unsigned short* Hb = (const unsigned short*)Hraw;
    const float* Hf = (const float*)Hraw;

    // ---- Phase 1: each wave aggregates 4 nodes ----
    for (int i = 0; i < 4; i++) {
        int node = base + wave * 4 + i;
        int start = 0, len = 0;
        if (node < N) {
            start = rowptr[node];
            len = counts[node];
        }
        start = __builtin_amdgcn_readfirstlane(start);
        len = __builtin_amdgcn_readfirstlane(len);
        const int2* ep = edgedat + start;

        float acc[8];
#pragma unroll
        for (int u = 0; u < 8; u++) acc[u] = 0.f;

        int j = 0;
        if (a_fp32) {
            for (; j + 4 <= len; j += 4) {
                int2 e = ep[j + grp];
                const float* hp = Hf + (size_t)e.x * 128 + gl * 8;
                float4 a0 = *(const float4*)(const void*)hp;
                float4 a1 = *(const float4*)(const void*)(hp + 4);
                float w = __int_as_float(e.y);
                acc[0] += w * a0.x; acc[1] += w * a0.y; acc[2] += w * a0.z; acc[3] += w * a0.w;
                acc[4] += w * a1.x; acc[5] += w * a1.y; acc[6] += w * a1.z; acc[7] += w * a1.w;
            }
            int rem = len - j;
            if (grp < rem) {
                int2 e = ep[j + grp];
                const float* hp = Hf + (size_t)e.x * 128 + gl * 8;
                float4 a0 = *(const float4*)(const void*)hp;
                float4 a1 = *(const float4*)(const void*)(hp + 4);
                float w = __int_as_float(e.y);
                acc[0] += w * a0.x; acc[1] += w * a0.y; acc[2] += w * a0.z; acc[3] += w * a0.w;
                acc[4] += w * a1.x; acc[5] += w * a1.y; acc[6] += w * a1.z; acc[7] += w * a1.w;
            }
        } else {
            for (; j + 8 <= len; j += 8) {
                int2 e0 = ep[j + grp];
                int2 e1 = ep[j + 4 + grp];
                short8 h0 = *(const short8*)(const void*)(Hb + (size_t)e0.x * 128 + gl * 8);
                short8 h1 = *(const short8*)(const void*)(Hb + (size_t)e1.x * 128 + gl * 8);
                float w0 = __int_as_float(e0.y);
                float w1 = __int_as_float(e1.y);
#pragma unroll
                for (int u = 0; u < 8; u++) acc[u] += w0 * bf2f((unsigned short)h0[u]);
#pragma unroll
                for (int u = 0; u < 8; u++) acc[u] += w1 * bf2f((unsigned short)h1[u]);
            }
            for (; j + 4 <= len; j += 4) {
                int2 e = ep[j + grp];
                short8 h = *(const short8*)(const void*)(Hb + (size_t)e.x * 128 + gl * 8);
                float w = __int_as_float(e.y);
#pragma unroll
                for (int u = 0; u < 8; u++) acc[u] += w * bf2f((unsigned short)h[u]);
            }
            int rem = len - j;
            if (grp < rem) {
                int2 e = ep[j + grp];
                short8 h = *(const short8*)(const void*)(Hb + (size_t)e.x * 128 + gl * 8);
                float w = __int_as_float(e.y);
#pragma unroll
                for (int u = 0; u < 8; u++) acc[u] += w * bf2f((unsigned short)h[u]);
            }
        }

#pragma unroll
        for (int u = 0; u < 8; u++) {
            acc[u] += __shfl_xor(acc[u], 16, 64);
            acc[u] += __shfl_xor(acc[u], 32, 64);
        }

        if (grp == 0) {
            short8 o;
#pragma unroll
            for (int u = 0; u < 8; u++) o[u] = (short)f2bf(acc[u]);
            *(short8*)(void*)(&agg[(wave * 4 + i) * LDA + gl * 8]) = o;
        }
    }

    __syncthreads();

    // ---- Phase 2: MFMA from LDS agg tile x global Wt ----
    const int quad = lane >> 4;
    const int r16 = lane & 15;

    if constexpr (!SM) {
        // FOUT = 128: wave computes col-tiles {2*wave, 2*wave+1}
        short8 afrag[4];
#pragma unroll
        for (int kk = 0; kk < 4; kk++)
            afrag[kk] = *(const short8*)(const void*)(&agg[r16 * LDA + kk * 32 + quad * 8]);

        f32x4 acc2[2];
#pragma unroll
        for (int t = 0; t < 2; t++) acc2[t] = (f32x4){0.f, 0.f, 0.f, 0.f};

#pragma unroll
        for (int kk = 0; kk < 4; kk++) {
#pragma unroll
            for (int t = 0; t < 2; t++) {
                int ntg = wave * 2 + t;
                short8 b = *(const short8*)(const void*)(wt + (size_t)(ntg * 16 + r16) * 128 + kk * 32 + quad * 8);
                acc2[t] = __builtin_amdgcn_mfma_f32_16x16x32_bf16(afrag[kk], b, acc2[t], 0, 0, 0);
            }
        }

        unsigned short* ob = (unsigned short*)out;
#pragma unroll
        for (int t = 0; t < 2; t++) {
            int ntg = wave * 2 + t;
#pragma unroll
            for (int r = 0; r < 4; r++) {
                float v = fmaxf(acc2[t][r], 0.f);
                float o = __shfl_xor(v, 1, 64);
                int row = base + quad * 4 + r;
                if (((lane & 1) == 0) && row < N) {
                    __hip_bfloat162 pk;
                    pk.x = __float2bfloat16(v);
                    pk.y = __float2bfloat16(o);
                    *(__hip_bfloat162*)(ob + (size_t)row * 128 + ntg * 16 + r16) = pk;
                }
            }
        }
    } else {
        // FOUT = 64 + relu + softmax: wave 0 only
        if (wave != 0) return;
        short8 afrag[4];
#pragma unroll
        for (int kk = 0; kk < 4; kk++)
            afrag[kk] = *(const short8*)(const void*)(&agg[r16 * LDA + kk * 32 + quad * 8]);

        f32x4 acc3[4];
#pragma unroll
        for (int nt = 0; nt < 4; nt++) acc3[nt] = (f32x4){0.f, 0.f, 0.f, 0.f};
#pragma unroll
        for (int kk = 0; kk < 4; kk++) {
#pragma unroll
            for (int nt = 0; nt < 4; nt++) {
                short8 b = *(const short8*)(const void*)(wt + (size_t)(nt * 16 + r16) * 128 + kk * 32 + quad * 8);
                acc3[nt] = __builtin_amdgcn_mfma_f32_16x16x32_bf16(afrag[kk], b, acc3[nt], 0, 0, 0);
            }
        }

        const int out_fp32 = flags[0];
#pragma unroll
        for (int r = 0; r < 4; r++) {
            // row = quad*4 + r; cols nt*16 + r16
            float v0 = fmaxf(acc3[0][r], 0.f);
            float v1 = fmaxf(acc3[1][r], 0.f);
            float v2 = fmaxf(acc3[2][r], 0.f);
            float v3 = fmaxf(acc3[3][r], 0.f);
            float m = fmaxf(fmaxf(v0, v1), fmaxf(v2, v3));
#pragma unroll
            for (int off = 1; off < 16; off <<= 1) m = fmaxf(m, __shfl_xor(m, off, 64));
            float e0 = __expf(v0 - m), e1 = __expf(v1 - m), e2 = __expf(v2 - m), e3 = __expf(v3 - m);
            float s = e0 + e1 + e2 + e3;
#pragma unroll
            for (int off = 1; off < 16; off <<= 1) s += __shfl_xor(s, off, 64);
            float inv = 1.0f / s;
            float rv[4] = {e0 * inv, e1 * inv, e2 * inv, e3 * inv};
            int row = base + quad * 4 + r;
            if (out_fp32) {
                if (row < N) {
                    float* op = (float*)out + (size_t)row * 64;
#pragma unroll
                    for (int nt = 0; nt < 4; nt++) op[nt * 16 + r16] = rv[nt];
                }
            } else {
#pragma unroll
                for (int nt = 0; nt < 4; nt++) {
                    float o = __shfl_xor(rv[nt], 1, 64);
                    if (((lane & 1) == 0) && row < N) {
                        __hip_bfloat162 pk;
                        pk.x = __float2bfloat16(rv[nt]);
                        pk.y = __float2bfloat16(o);
                        *(__hip_bfloat162*)((unsigned short*)out + (size_t)row * 64 + nt * 16 + r16) = pk;
                    }
                }
            }
        }
    }
}

// ---------------- launch ----------------

extern "C" void kernel_launch(void* const* d_in, const int* in_sizes, int n_in,
                              void* d_out, int out_size, void* d_ws, size_t ws_size,
                              hipStream_t stream) {
    const void* X  = d_in[0];                       // [N,128] bf16 or fp32
    const int*  ei = (const int*)d_in[1];           // [2,E] int32 or int64
    const void* W1 = d_in[2];                       // [128,128]
    const void* W2 = d_in[3];                       // [128,128]
    const void* W3 = d_in[4];                       // [128,64]

    const int N = in_sizes[0] / 128;   // 50000
    const int E = in_sizes[1] / 2;     // 800000

    char* ws = (char*)d_ws;
    size_t off = 0;
    int* counts = (int*)(ws + off);   off += ws_align((size_t)N * 4);
    int* total  = (int*)(ws + off);   off += ws_align(64);
    const size_t zero_bytes = off;    // counts + total need zeroing
    int* flags    = (int*)(ws + off);   off += ws_align(64);
    int* rowptr   = (int*)(ws + off);   off += ws_align((size_t)N * 4);
    float* dinv   = (float*)(ws + off); off += ws_align((size_t)N * 4);
    int* loff     = (int*)(ws + off);   off += ws_align((size_t)E * 4);
    int2* edgedat = (int2*)(ws + off);  off += ws_align((size_t)E * 8);
    unsigned short* H1 = (unsigned short*)(ws + off); off += ws_align((size_t)N * 128 * 2);
    unsigned short* H2 = (unsigned short*)(ws + off); off += ws_align((size_t)N * 128 * 2);
    unsigned short* wt1 = (unsigned short*)(ws + off); off += ws_align(16384 * 2);
    unsigned short* wt2 = (unsigned short*)(ws + off); off += ws_align(16384 * 2);
    unsigned short* wt3 = (unsigned short*)(ws + off); off += ws_align(8192 * 2);

    hipMemsetAsync(d_ws, 0, zero_bytes, stream);

    const int hblocks = (E + 255) / 256;       // 3125
    const int fblocks = (N + 15) / 16;         // 3125

    // K0: hist + wconv + flags
    hist_wconv_kernel<<<hblocks + 160, 256, 0, stream>>>(
        ei, (const unsigned short*)W1, W1, W2, W3, counts, loff, flags, wt1, wt2, wt3, E, hblocks);
    alloc_kernel<<<(N + 255) / 256, 256, 0, stream>>>(counts, dinv, rowptr, total, N);
    fill_kernel<<<hblocks, 256, 0, stream>>>(ei, flags, dinv, rowptr, loff, edgedat, E);

    // layer 1: H1 = relu( agg(X) @ W1 )
    fused_layer_kernel<128, false><<<fblocks, 256, 0, stream>>>(
        X, 1, wt1, edgedat, rowptr, counts, flags, H1, N);
    // layer 2: H2 = relu( agg(H1) @ W2 )
    fused_layer_kernel<128, false><<<fblocks, 256, 0, stream>>>(
        H1, 0, wt2, edgedat, rowptr, counts, flags, H2, N);
    // layer 3: out = softmax( relu( agg(H2) @ W3 ) )
    fused_layer_kernel<64, true><<<fblocks, 256, 0, stream>>>(
        H2, 0, wt3, edgedat, rowptr, counts, flags, d_out, N);
}